// Round 2
// baseline (408.896 us; speedup 1.0000x reference)
//
#include <hip/hip_runtime.h>
#include <stdint.h>

typedef unsigned short u16;
typedef __bf16 bf16x8 __attribute__((ext_vector_type(8)));
typedef float f32x4 __attribute__((ext_vector_type(4)));

#define B_ 2
#define T_ 2048

// ---------- helpers ----------
__device__ __forceinline__ u16 f2b(float f) {
  unsigned u = __float_as_uint(f);
  u += 0x7fffu + ((u >> 16) & 1u);
  return (u16)(u >> 16);
}
__device__ __forceinline__ float b2f(u16 v) {
  return __uint_as_float(((unsigned)v) << 16);
}
__device__ __forceinline__ unsigned cvt_pk(float lo, float hi) {
  unsigned r;
  asm("v_cvt_pk_bf16_f32 %0, %1, %2" : "=v"(r) : "v"(lo), "v"(hi));
  return r;
}

using gu32 = __attribute__((address_space(1))) const unsigned int;
using lu32 = __attribute__((address_space(3))) unsigned int;
__device__ __forceinline__ void gl_lds16(const u16* g, u16* l) {
  __builtin_amdgcn_global_load_lds((gu32*)g, (lu32*)l, 16, 0, 0);
}

// ---------- convert x fp32 -> bf16 ----------
__global__ __launch_bounds__(256) void conv_x_kernel(const float* __restrict__ in,
                                                     u16* __restrict__ out) {
  int i = (blockIdx.x * 256 + threadIdx.x) * 4;
  float4 v = *reinterpret_cast<const float4*>(in + i);
  union { u16 h[4]; unsigned long long ll; } pk;
  pk.h[0] = f2b(v.x); pk.h[1] = f2b(v.y); pk.h[2] = f2b(v.z); pk.h[3] = f2b(v.w);
  *reinterpret_cast<unsigned long long*>(out + i) = pk.ll;
}

// ---------- transpose weight fp32 [K][N] -> bf16 Wt[row_off+n][k] ----------
__global__ __launch_bounds__(256) void transpose_w_kernel(const float* __restrict__ W,
                                                          int K, int N,
                                                          u16* __restrict__ Wt,
                                                          int ldt, int row_off) {
  __shared__ float tile[32][33];
  int n0 = blockIdx.x * 32, k0 = blockIdx.y * 32;
  int cx = threadIdx.x, ry = threadIdx.y;
  #pragma unroll
  for (int i = 0; i < 4; i++)
    tile[ry + i * 8][cx] = W[(size_t)(k0 + ry + i * 8) * N + n0 + cx];
  __syncthreads();
  #pragma unroll
  for (int i = 0; i < 4; i++)
    Wt[(size_t)(row_off + n0 + ry + i * 8) * ldt + k0 + cx] = f2b(tile[cx][ry + i * 8]);
}

// ---------- GEMM (m97 structure): C[M][N] = A[M][K] * Bt[N][K]^T ----------
// grid (N/128, M/128), 256 thr (4 waves), wave -> 64x64 via 4x4 16x16x32 MFMA.
// Staging: global_load_lds width-16 into linear [128][32] LDS tiles.
__global__ __launch_bounds__(256) void gemm_bt(const u16* __restrict__ A, int lda,
                                               const u16* __restrict__ Bt, int ldb,
                                               void* __restrict__ Cout, int ldc,
                                               int K, int f32out, u16* __restrict__ vt) {
  __shared__ u16 As[128 * 32];
  __shared__ u16 Bs[128 * 32];
  const int tid = threadIdx.x;
  const int wave = tid >> 6, lane = tid & 63;
  const int wr = wave >> 1, wc = wave & 1;
  const int l15 = lane & 15, l4 = lane >> 4;
  const int m0 = blockIdx.y * 128, n0 = blockIdx.x * 128;
  const int lr = lane >> 2;          // row within 16-row chunk
  const int lc = (lane & 3) * 8;     // k col (u16)

  f32x4 acc[4][4];
  const f32x4 fzero = {0.f, 0.f, 0.f, 0.f};
  #pragma unroll
  for (int m = 0; m < 4; m++)
    #pragma unroll
    for (int n = 0; n < 4; n++)
      acc[m][n] = fzero;

  // per-wave: A rows [wave*32, wave*32+32), same for B
  const u16* gA  = A  + (size_t)(m0 + wave * 32 + lr) * lda + lc;
  const u16* gA2 = gA + (size_t)16 * lda;
  const u16* gB  = Bt + (size_t)(n0 + wave * 32 + lr) * ldb + lc;
  const u16* gB2 = gB + (size_t)16 * ldb;
  u16* lA  = &As[(wave * 32) * 32];      // wave-uniform LDS bases
  u16* lA2 = &As[(wave * 32 + 16) * 32];
  u16* lB  = &Bs[(wave * 32) * 32];
  u16* lB2 = &Bs[(wave * 32 + 16) * 32];

  for (int k0 = 0; k0 < K; k0 += 32) {
    __syncthreads();
    gl_lds16(gA + k0, lA);
    gl_lds16(gA2 + k0, lA2);
    gl_lds16(gB + k0, lB);
    gl_lds16(gB2 + k0, lB2);
    __syncthreads();
    bf16x8 af[4], bfr[4];
    #pragma unroll
    for (int m = 0; m < 4; m++)
      af[m] = *reinterpret_cast<const bf16x8*>(&As[(wr * 64 + m * 16 + l15) * 32 + l4 * 8]);
    #pragma unroll
    for (int n = 0; n < 4; n++)
      bfr[n] = *reinterpret_cast<const bf16x8*>(&Bs[(wc * 64 + n * 16 + l15) * 32 + l4 * 8]);
    #pragma unroll
    for (int m = 0; m < 4; m++)
      #pragma unroll
      for (int n = 0; n < 4; n++)
        acc[m][n] = __builtin_amdgcn_mfma_f32_16x16x32_bf16(af[m], bfr[n], acc[m][n], 0, 0, 0);
  }

  const int row_base = m0 + wr * 64 + l4 * 4;
  const int col_base = n0 + wc * 64 + l15;
  if (f32out) {
    float* Cf = (float*)Cout;
    #pragma unroll
    for (int m = 0; m < 4; m++)
      #pragma unroll
      for (int n = 0; n < 4; n++)
        #pragma unroll
        for (int r = 0; r < 4; r++)
          Cf[(size_t)(row_base + m * 16 + r) * ldc + col_base + n * 16] = acc[m][n][r];
  } else {
    u16* Cb = (u16*)Cout;
    #pragma unroll
    for (int m = 0; m < 4; m++)
      #pragma unroll
      for (int n = 0; n < 4; n++)
        #pragma unroll
        for (int r = 0; r < 4; r++)
          Cb[(size_t)(row_base + m * 16 + r) * ldc + col_base + n * 16] = f2b(acc[m][n][r]);
    if (vt) {
      // also emit transposed copy of the first 1024 cols (V content):
      // VT[(b*1024 + col)][t], ld 2048, where row m = b*2048 + t
      #pragma unroll
      for (int m = 0; m < 4; m++)
        #pragma unroll
        for (int n = 0; n < 4; n++) {
          int col = col_base + n * 16;
          if (col < 1024) {
            int mm = row_base + m * 16;
            int bb = mm >> 11, tt = mm & 2047;
            uint2 pk2;
            pk2.x = cvt_pk(acc[m][n][0], acc[m][n][1]);
            pk2.y = cvt_pk(acc[m][n][2], acc[m][n][3]);
            *reinterpret_cast<uint2*>(&vt[(size_t)(bb * 1024 + col) * 2048 + tt]) = pk2;
          }
        }
    }
  }
}

// ---------- rope (in place on cols [1024,2048) of [4096][2048] bf16) ----------
__global__ __launch_bounds__(256) void rope_kernel(u16* __restrict__ buf,
                                                   const float* __restrict__ cosT,
                                                   const float* __restrict__ sinT) {
  int idx = blockIdx.x * 256 + threadIdx.x;   // 4096 rows * 16 heads * 4 chunks
  int i8 = (idx & 3) * 8;
  int hh = (idx >> 2) & 15;
  int r  = idx >> 6;
  int t  = r & (T_ - 1);
  size_t base = (size_t)r * 2048 + 1024 + hh * 64;
  uint4 pa = *reinterpret_cast<const uint4*>(&buf[base + i8]);
  uint4 pb = *reinterpret_cast<const uint4*>(&buf[base + i8 + 32]);
  const u16* ap = reinterpret_cast<const u16*>(&pa);
  const u16* bp = reinterpret_cast<const u16*>(&pb);
  const float* cp = cosT + t * 64 + i8;
  const float* sp = sinT + t * 64 + i8;
  float y1[8], y2[8];
  #pragma unroll
  for (int j = 0; j < 8; j++) {
    float x1 = b2f(ap[j]), x2 = b2f(bp[j]);
    y1[j] = x1 * cp[j] - x2 * sp[j];
    y2[j] = x2 * cp[j + 32] + x1 * sp[j + 32];
  }
  uint4 o1, o2;
  o1.x = cvt_pk(y1[0], y1[1]); o1.y = cvt_pk(y1[2], y1[3]);
  o1.z = cvt_pk(y1[4], y1[5]); o1.w = cvt_pk(y1[6], y1[7]);
  o2.x = cvt_pk(y2[0], y2[1]); o2.y = cvt_pk(y2[2], y2[3]);
  o2.z = cvt_pk(y2[4], y2[5]); o2.w = cvt_pk(y2[6], y2[7]);
  *reinterpret_cast<uint4*>(&buf[base + i8]) = o1;
  *reinterpret_cast<uint4*>(&buf[base + i8 + 32]) = o2;
}

// ---------- causal flash attention, swapped QK^T, no K/V LDS ----------
// grid 1024 blocks x 256 thr; bid -> (bh = bid&31, qi = 31 - bid>>5) for XCD
// locality + LPT order. 4 independent waves, wave w owns q rows q0+16w..+16.
__global__ __launch_bounds__(256) void attn_kernel(const u16* __restrict__ qo,
                                                   const u16* __restrict__ kvo,
                                                   const u16* __restrict__ vtg,
                                                   u16* __restrict__ yb) {
  __shared__ u16 P_lds[4][16][72];   // per-wave P roundtrip, padded
  const int tid = threadIdx.x;
  const int wave = tid >> 6, lane = tid & 63;
  const int l15 = lane & 15, l4 = lane >> 4;
  const int bid = blockIdx.x;
  const int bh = bid & 31;
  const int qi = 31 - (bid >> 5);
  const int b = bh >> 4, h = bh & 15;
  const int q0 = qi * 64;
  const int qrow = q0 + wave * 16 + l15;

  // Q fragments (B-operand layout == A-operand layout: Q[q=l15][d=l4*8+j])
  const u16* qb = qo + (size_t)(b * T_ + qrow) * 2048 + h * 64;
  bf16x8 qf[4];
  qf[0] = *reinterpret_cast<const bf16x8*>(qb + l4 * 8);
  qf[1] = *reinterpret_cast<const bf16x8*>(qb + 32 + l4 * 8);
  qf[2] = *reinterpret_cast<const bf16x8*>(qb + 1024 + l4 * 8);
  qf[3] = *reinterpret_cast<const bf16x8*>(qb + 1056 + l4 * 8);

  const f32x4 fzero = {0.f, 0.f, 0.f, 0.f};
  f32x4 oT[4];   // O^T frags: rows d = f*16 + l4*4 + r, col q = l15
  #pragma unroll
  for (int f = 0; f < 4; f++) oT[f] = fzero;
  float m_run = -1e30f, l_run = 0.f;

  const u16* Kbase = kvo + (size_t)(b * T_) * 2048 + h * 64;
  const u16* Vbase = vtg + (size_t)(b * 1024 + h * 64) * 2048;

  for (int kv0 = 0; kv0 <= q0; kv0 += 64) {
    // swapped QK^T: sT[c] = K_tile(c) x Q  -> P^T[kv=c*16+l4*4+r][q=l15]
    f32x4 sT[4];
    #pragma unroll
    for (int c = 0; c < 4; c++) sT[c] = fzero;
    #pragma unroll
    for (int c = 0; c < 4; c++) {
      const u16* kr = Kbase + (size_t)(kv0 + c * 16 + l15) * 2048;
      bf16x8 k0f = *reinterpret_cast<const bf16x8*>(kr + l4 * 8);
      bf16x8 k1f = *reinterpret_cast<const bf16x8*>(kr + 32 + l4 * 8);
      bf16x8 k2f = *reinterpret_cast<const bf16x8*>(kr + 1024 + l4 * 8);
      bf16x8 k3f = *reinterpret_cast<const bf16x8*>(kr + 1056 + l4 * 8);
      sT[c] = __builtin_amdgcn_mfma_f32_16x16x32_bf16(k0f, qf[0], sT[c], 0, 0, 0);
      sT[c] = __builtin_amdgcn_mfma_f32_16x16x32_bf16(k1f, qf[1], sT[c], 0, 0, 0);
      sT[c] = __builtin_amdgcn_mfma_f32_16x16x32_bf16(k2f, qf[2], sT[c], 0, 0, 0);
      sT[c] = __builtin_amdgcn_mfma_f32_16x16x32_bf16(k3f, qf[3], sT[c], 0, 0, 0);
    }

    // softmax: all 16 p-values belong to q = l15 -> lane-local + 2 shfl
    const bool diag = (kv0 == q0);
    float p[4][4];
    float mx = -1e30f;
    #pragma unroll
    for (int c = 0; c < 4; c++)
      #pragma unroll
      for (int r = 0; r < 4; r++) {
        float s = sT[c][r] * 0.125f;
        if (diag) {
          int kv = kv0 + c * 16 + l4 * 4 + r;
          if (kv > qrow) s = -1e30f;
        }
        p[c][r] = s;
        mx = fmaxf(mx, s);
      }
    mx = fmaxf(mx, __shfl_xor(mx, 16));
    mx = fmaxf(mx, __shfl_xor(mx, 32));
    float m_new = fmaxf(m_run, mx);
    float corr = __expf(m_run - m_new);
    float rsum = 0.f;
    #pragma unroll
    for (int c = 0; c < 4; c++)
      #pragma unroll
      for (int r = 0; r < 4; r++) {
        float pe = __expf(p[c][r] - m_new);
        p[c][r] = pe;
        rsum += pe;
      }
    rsum += __shfl_xor(rsum, 16);
    rsum += __shfl_xor(rsum, 32);
    l_run = l_run * corr + rsum;
    m_run = m_new;
    #pragma unroll
    for (int f = 0; f < 4; f++) oT[f] *= corr;

    // P^T quads -> per-wave LDS (vectorized), reread as B-frag rows
    #pragma unroll
    for (int c = 0; c < 4; c++) {
      uint2 pk2;
      pk2.x = cvt_pk(p[c][0], p[c][1]);
      pk2.y = cvt_pk(p[c][2], p[c][3]);
      *reinterpret_cast<uint2*>(&P_lds[wave][l15][c * 16 + l4 * 4]) = pk2;
    }
    bf16x8 pb0 = *reinterpret_cast<const bf16x8*>(&P_lds[wave][l15][l4 * 8]);
    bf16x8 pb1 = *reinterpret_cast<const bf16x8*>(&P_lds[wave][l15][32 + l4 * 8]);

    // PV: O^T += V^T x P^T  (A = V^T from VT buffer, b128 rows)
    #pragma unroll
    for (int f = 0; f < 4; f++) {
      const u16* vr = Vbase + (size_t)(f * 16 + l15) * 2048 + kv0;
      bf16x8 v0 = *reinterpret_cast<const bf16x8*>(vr + l4 * 8);
      bf16x8 v1 = *reinterpret_cast<const bf16x8*>(vr + 32 + l4 * 8);
      oT[f] = __builtin_amdgcn_mfma_f32_16x16x32_bf16(v0, pb0, oT[f], 0, 0, 0);
      oT[f] = __builtin_amdgcn_mfma_f32_16x16x32_bf16(v1, pb1, oT[f], 0, 0, 0);
    }
  }

  const float inv = 1.f / l_run;
  #pragma unroll
  for (int f = 0; f < 4; f++) {
    uint2 pk2;
    pk2.x = cvt_pk(oT[f][0] * inv, oT[f][1] * inv);
    pk2.y = cvt_pk(oT[f][2] * inv, oT[f][3] * inv);
    *reinterpret_cast<uint2*>(
        &yb[(size_t)(b * T_ + qrow) * 1024 + h * 64 + f * 16 + l4 * 4]) = pk2;
  }
}

// ---------- launcher ----------
extern "C" void kernel_launch(void* const* d_in, const int* in_sizes, int n_in,
                              void* d_out, int out_size, void* d_ws, size_t ws_size,
                              hipStream_t stream) {
  const float* x         = (const float*)d_in[0];
  const float* cosT      = (const float*)d_in[1];
  const float* sinT      = (const float*)d_in[2];
  const float* W_kv_down = (const float*)d_in[3];
  const float* W_kv_up   = (const float*)d_in[4];
  const float* W_k_rope  = (const float*)d_in[5];
  const float* W_q_down  = (const float*)d_in[6];
  const float* W_q_up    = (const float*)d_in[7];
  const float* W_q_rope  = (const float*)d_in[8];
  const float* W_out     = (const float*)d_in[9];
  float* out = (float*)d_out;
  char* ws = (char*)d_ws;

  // ws layout (bytes), total ~61.6 MB
  u16* xb    = (u16*)(ws + 0);              // 4096x1024 (reused as yb)
  u16* lat   = (u16*)(ws + 8388608);        // 4096x640
  u16* WdT   = (u16*)(ws + 13631488);       // 640x1024
  u16* WkvT  = (u16*)(ws + 14942208);       // 2048x256
  u16* WqT   = (u16*)(ws + 15990784);       // 2048x384
  u16* WoutT = (u16*)(ws + 17563648);       // 1024x1024
  u16* kvo   = (u16*)(ws + 19660800);       // 4096x2048 (kv_up | k_rope)
  u16* qo    = (u16*)(ws + 36438016);       // 4096x2048 (q_up | q_rope)
  u16* VT    = (u16*)(ws + 53215232);       // [2][1024][2048] V^T
  u16* yb    = (u16*)(ws + 0);

  dim3 tb(32, 8);
  conv_x_kernel<<<4096, 256, 0, stream>>>(x, xb);
  transpose_w_kernel<<<dim3(8, 32),  tb, 0, stream>>>(W_kv_down, 1024, 256,  WdT,  1024, 0);
  transpose_w_kernel<<<dim3(12, 32), tb, 0, stream>>>(W_q_down,  1024, 384,  WdT,  1024, 256);
  transpose_w_kernel<<<dim3(32, 8),  tb, 0, stream>>>(W_kv_up,   256,  1024, WkvT, 256,  0);
  transpose_w_kernel<<<dim3(32, 8),  tb, 0, stream>>>(W_k_rope,  256,  1024, WkvT, 256,  1024);
  transpose_w_kernel<<<dim3(32, 12), tb, 0, stream>>>(W_q_up,    384,  1024, WqT,  384,  0);
  transpose_w_kernel<<<dim3(32, 12), tb, 0, stream>>>(W_q_rope,  384,  1024, WqT,  384,  1024);
  transpose_w_kernel<<<dim3(32, 32), tb, 0, stream>>>(W_out,     1024, 1024, WoutT, 1024, 0);

  // lat = xb @ [W_kv_down | W_q_down]
  gemm_bt<<<dim3(5, 32), 256, 0, stream>>>(xb, 1024, WdT, 1024, lat, 640, 1024, 0, nullptr);
  // kvo = lat[:, :256] @ [W_kv_up | W_k_rope]  (+ VT transposed copy of V cols)
  gemm_bt<<<dim3(16, 32), 256, 0, stream>>>(lat, 640, WkvT, 256, kvo, 2048, 256, 0, VT);
  // qo = lat[:, 256:] @ [W_q_up | W_q_rope]
  gemm_bt<<<dim3(16, 32), 256, 0, stream>>>(lat + 256, 640, WqT, 384, qo, 2048, 384, 0, nullptr);

  rope_kernel<<<1024, 256, 0, stream>>>(kvo, cosT, sinT);
  rope_kernel<<<1024, 256, 0, stream>>>(qo, cosT, sinT);

  attn_kernel<<<1024, 256, 0, stream>>>(qo, kvo, VT, yb);

  // out = yb @ W_out (fp32)
  gemm_bt<<<dim3(8, 32), 256, 0, stream>>>(yb, 1024, WoutT, 1024, out, 1024, 1024, 1, nullptr);
}

// Round 3
// 248.917 us; speedup vs baseline: 1.6427x; 1.6427x over previous
//
#include <hip/hip_runtime.h>
#include <stdint.h>

typedef unsigned short u16;
typedef __bf16 bf16x8 __attribute__((ext_vector_type(8)));
typedef float f32x4 __attribute__((ext_vector_type(4)));

#define B_ 2
#define T_ 2048

// ---------- helpers ----------
__device__ __forceinline__ u16 f2b(float f) {
  unsigned u = __float_as_uint(f);
  u += 0x7fffu + ((u >> 16) & 1u);
  return (u16)(u >> 16);
}
__device__ __forceinline__ float b2f(u16 v) {
  return __uint_as_float(((unsigned)v) << 16);
}
__device__ __forceinline__ unsigned cvt_pk(float lo, float hi) {
  unsigned r;
  asm("v_cvt_pk_bf16_f32 %0, %1, %2" : "=v"(r) : "v"(lo), "v"(hi));
  return r;
}

using gu32 = __attribute__((address_space(1))) const unsigned int;
using lu32 = __attribute__((address_space(3))) unsigned int;
__device__ __forceinline__ void gl_lds16(const u16* g, u16* l) {
  __builtin_amdgcn_global_load_lds((gu32*)g, (lu32*)l, 16, 0, 0);
}

// ---------- convert x fp32 -> bf16 ----------
__global__ __launch_bounds__(256) void conv_x_kernel(const float* __restrict__ in,
                                                     u16* __restrict__ out) {
  int i = (blockIdx.x * 256 + threadIdx.x) * 4;
  float4 v = *reinterpret_cast<const float4*>(in + i);
  union { u16 h[4]; unsigned long long ll; } pk;
  pk.h[0] = f2b(v.x); pk.h[1] = f2b(v.y); pk.h[2] = f2b(v.z); pk.h[3] = f2b(v.w);
  *reinterpret_cast<unsigned long long*>(out + i) = pk.ll;
}

// ---------- transpose weight fp32 [K][N] -> bf16 Wt[row_off+n][k] ----------
__global__ __launch_bounds__(256) void transpose_w_kernel(const float* __restrict__ W,
                                                          int K, int N,
                                                          u16* __restrict__ Wt,
                                                          int ldt, int row_off) {
  __shared__ float tile[32][33];
  int n0 = blockIdx.x * 32, k0 = blockIdx.y * 32;
  int cx = threadIdx.x, ry = threadIdx.y;
  #pragma unroll
  for (int i = 0; i < 4; i++)
    tile[ry + i * 8][cx] = W[(size_t)(k0 + ry + i * 8) * N + n0 + cx];
  __syncthreads();
  #pragma unroll
  for (int i = 0; i < 4; i++)
    Wt[(size_t)(row_off + n0 + ry + i * 8) * ldt + k0 + cx] = f2b(tile[cx][ry + i * 8]);
}

// ---------- GEMM (m97 structure + 2-phase dbuf): C = A * Bt^T ----------
__global__ __launch_bounds__(256) void gemm_bt(const u16* __restrict__ A, int lda,
                                               const u16* __restrict__ Bt, int ldb,
                                               void* __restrict__ Cout, int ldc,
                                               int K, int f32out, u16* __restrict__ vt) {
  __shared__ u16 As[2][128 * 32];
  __shared__ u16 Bs[2][128 * 32];
  const int tid = threadIdx.x;
  const int wave = tid >> 6, lane = tid & 63;
  const int wr = wave >> 1, wc = wave & 1;
  const int l15 = lane & 15, l4 = lane >> 4;
  const int m0 = blockIdx.y * 128, n0 = blockIdx.x * 128;
  const int lr = lane >> 2;          // row within 16-row chunk
  const int lc = (lane & 3) * 8;     // k col (u16)

  f32x4 acc[4][4];
  const f32x4 fzero = {0.f, 0.f, 0.f, 0.f};
  #pragma unroll
  for (int m = 0; m < 4; m++)
    #pragma unroll
    for (int n = 0; n < 4; n++)
      acc[m][n] = fzero;

  const u16* gA  = A  + (size_t)(m0 + wave * 32 + lr) * lda + lc;
  const u16* gA2 = gA + (size_t)16 * lda;
  const u16* gB  = Bt + (size_t)(n0 + wave * 32 + lr) * ldb + lc;
  const u16* gB2 = gB + (size_t)16 * ldb;

  auto stage = [&](int buf, int k0) {
    u16* lA  = &As[buf][(wave * 32) * 32];
    u16* lA2 = &As[buf][(wave * 32 + 16) * 32];
    u16* lB  = &Bs[buf][(wave * 32) * 32];
    u16* lB2 = &Bs[buf][(wave * 32 + 16) * 32];
    gl_lds16(gA + k0, lA);
    gl_lds16(gA2 + k0, lA2);
    gl_lds16(gB + k0, lB);
    gl_lds16(gB2 + k0, lB2);
  };

  stage(0, 0);
  __syncthreads();
  int buf = 0;
  for (int k0 = 0; k0 < K; k0 += 32) {
    if (k0 + 32 < K) stage(buf ^ 1, k0 + 32);
    bf16x8 af[4], bfr[4];
    #pragma unroll
    for (int m = 0; m < 4; m++)
      af[m] = *reinterpret_cast<const bf16x8*>(&As[buf][(wr * 64 + m * 16 + l15) * 32 + l4 * 8]);
    #pragma unroll
    for (int n = 0; n < 4; n++)
      bfr[n] = *reinterpret_cast<const bf16x8*>(&Bs[buf][(wc * 64 + n * 16 + l15) * 32 + l4 * 8]);
    #pragma unroll
    for (int m = 0; m < 4; m++)
      #pragma unroll
      for (int n = 0; n < 4; n++)
        acc[m][n] = __builtin_amdgcn_mfma_f32_16x16x32_bf16(af[m], bfr[n], acc[m][n], 0, 0, 0);
    __syncthreads();
    buf ^= 1;
  }

  const int row_base = m0 + wr * 64 + l4 * 4;
  const int col_base = n0 + wc * 64 + l15;
  if (f32out) {
    float* Cf = (float*)Cout;
    #pragma unroll
    for (int m = 0; m < 4; m++)
      #pragma unroll
      for (int n = 0; n < 4; n++)
        #pragma unroll
        for (int r = 0; r < 4; r++)
          Cf[(size_t)(row_base + m * 16 + r) * ldc + col_base + n * 16] = acc[m][n][r];
  } else {
    u16* Cb = (u16*)Cout;
    #pragma unroll
    for (int m = 0; m < 4; m++)
      #pragma unroll
      for (int n = 0; n < 4; n++)
        #pragma unroll
        for (int r = 0; r < 4; r++)
          Cb[(size_t)(row_base + m * 16 + r) * ldc + col_base + n * 16] = f2b(acc[m][n][r]);
    if (vt) {
      // transposed copy of V content cols: VT[(b*1024+col)][t]
      #pragma unroll
      for (int m = 0; m < 4; m++)
        #pragma unroll
        for (int n = 0; n < 4; n++) {
          int col = col_base + n * 16;
          if (col < 1024) {
            int mm = row_base + m * 16;
            int bb = mm >> 11, tt = mm & 2047;
            uint2 pk2;
            pk2.x = cvt_pk(acc[m][n][0], acc[m][n][1]);
            pk2.y = cvt_pk(acc[m][n][2], acc[m][n][3]);
            *reinterpret_cast<uint2*>(&vt[(size_t)(bb * 1024 + col) * 2048 + tt]) = pk2;
          }
        }
    }
  }
}

// ---------- rope (in place on cols [1024,2048) of [4096][2048] bf16) ----------
__global__ __launch_bounds__(256) void rope_kernel(u16* __restrict__ buf,
                                                   const float* __restrict__ cosT,
                                                   const float* __restrict__ sinT) {
  int idx = blockIdx.x * 256 + threadIdx.x;
  int i8 = (idx & 3) * 8;
  int hh = (idx >> 2) & 15;
  int r  = idx >> 6;
  int t  = r & (T_ - 1);
  size_t base = (size_t)r * 2048 + 1024 + hh * 64;
  uint4 pa = *reinterpret_cast<const uint4*>(&buf[base + i8]);
  uint4 pb = *reinterpret_cast<const uint4*>(&buf[base + i8 + 32]);
  const u16* ap = reinterpret_cast<const u16*>(&pa);
  const u16* bp = reinterpret_cast<const u16*>(&pb);
  const float* cp = cosT + t * 64 + i8;
  const float* sp = sinT + t * 64 + i8;
  float y1[8], y2[8];
  #pragma unroll
  for (int j = 0; j < 8; j++) {
    float x1 = b2f(ap[j]), x2 = b2f(bp[j]);
    y1[j] = x1 * cp[j] - x2 * sp[j];
    y2[j] = x2 * cp[j + 32] + x1 * sp[j + 32];
  }
  uint4 o1, o2;
  o1.x = cvt_pk(y1[0], y1[1]); o1.y = cvt_pk(y1[2], y1[3]);
  o1.z = cvt_pk(y1[4], y1[5]); o1.w = cvt_pk(y1[6], y1[7]);
  o2.x = cvt_pk(y2[0], y2[1]); o2.y = cvt_pk(y2[2], y2[3]);
  o2.z = cvt_pk(y2[4], y2[5]); o2.w = cvt_pk(y2[6], y2[7]);
  *reinterpret_cast<uint4*>(&buf[base + i8]) = o1;
  *reinterpret_cast<uint4*>(&buf[base + i8 + 32]) = o2;
}

// ---------- causal flash attention ----------
// swapped QK^T (lane-local softmax) + swizzled LDS K/V staging via
// pre-swizzled global_load_lds source (rule 21) + 2-phase dbuf pipeline.
// grid 1024 x 256 thr; bh = bid&31 (XCD locality), qi = 31-bid>>5 (LPT).
__global__ __launch_bounds__(256) void attn_kernel(const u16* __restrict__ qo,
                                                   const u16* __restrict__ kvo,
                                                   const u16* __restrict__ vtg,
                                                   u16* __restrict__ yb) {
  __shared__ u16 K_lds[2][64 * 128];   // swizzled rows: byte ^= (row&7)<<4
  __shared__ u16 V_lds[2][64 * 64];    // V^T, same swizzle
  __shared__ u16 P_lds[4][16][72];
  const int tid = threadIdx.x;
  const int wave = tid >> 6, lane = tid & 63;
  const int l15 = lane & 15, l4 = lane >> 4;
  const int bid = blockIdx.x;
  const int bh = bid & 31;
  const int qi = 31 - (bid >> 5);
  const int b = bh >> 4, h = bh & 15;
  const int q0 = qi * 64;
  const int qrow = q0 + wave * 16 + l15;

  // Q fragments
  const u16* qb = qo + (size_t)(b * T_ + qrow) * 2048 + h * 64;
  bf16x8 qf[4];
  qf[0] = *reinterpret_cast<const bf16x8*>(qb + l4 * 8);
  qf[1] = *reinterpret_cast<const bf16x8*>(qb + 32 + l4 * 8);
  qf[2] = *reinterpret_cast<const bf16x8*>(qb + 1024 + l4 * 8);
  qf[3] = *reinterpret_cast<const bf16x8*>(qb + 1056 + l4 * 8);

  const u16* Kbase = kvo + (size_t)(b * T_) * 2048 + h * 64;
  const u16* Vbase = vtg + (size_t)(b * 1024 + h * 64) * 2048;

  // K stage: 4 issues/wave, issue j covers rows wave*16+j*4 .. +4
  const int krow_i = lane >> 4;            // row within 4-row issue chunk
  const int kc2 = (lane & 15) * 16;        // byte col in 256B row
  // V stage: 2 issues/wave, issue j covers rows wave*16+j*8 .. +8
  const int vrow_i = lane >> 3;
  const int vc2 = (lane & 7) * 16;         // byte col in 128B row

  auto stage = [&](int buf, int kv0) {
    #pragma unroll
    for (int j = 0; j < 4; j++) {
      int row = wave * 16 + j * 4 + krow_i;
      int c2x = kc2 ^ ((row & 7) << 4);    // pre-swizzled source col
      int cu = c2x >> 1;
      const u16* src = Kbase + (size_t)(kv0 + row) * 2048 + (cu < 64 ? cu : 960 + cu);
      gl_lds16(src, &K_lds[buf][(wave * 16 + j * 4) * 128]);
    }
    #pragma unroll
    for (int j = 0; j < 2; j++) {
      int row = wave * 16 + j * 8 + vrow_i;
      int c2x = vc2 ^ ((row & 7) << 4);
      const u16* src = Vbase + (size_t)row * 2048 + kv0 + (c2x >> 1);
      gl_lds16(src, &V_lds[buf][(wave * 16 + j * 8) * 64]);
    }
  };

  const f32x4 fzero = {0.f, 0.f, 0.f, 0.f};
  f32x4 oT[4];   // O^T frags: row d = f*16 + l4*4 + r, col q = l15
  #pragma unroll
  for (int f = 0; f < 4; f++) oT[f] = fzero;
  float m_run = -1e30f, l_run = 0.f;

  const int nt = qi + 1;
  stage(0, 0);
  __syncthreads();
  int buf = 0;

  for (int t = 0; t < nt; t++) {
    const int kv0 = t * 64;
    if (t + 1 < nt) stage(buf ^ 1, kv0 + 64);

    const char* Kb = (const char*)&K_lds[buf][0];
    const char* Vb = (const char*)&V_lds[buf][0];

    // swapped QK^T: sT[c] = K_tile(c) x Q -> P^T[kv=c*16+l4*4+r][q=l15]
    f32x4 sT[4];
    #pragma unroll
    for (int c = 0; c < 4; c++) sT[c] = fzero;
    #pragma unroll
    for (int c = 0; c < 4; c++) {
      const int krow = c * 16 + l15;
      const int kxm = (krow & 7) << 4;
      #pragma unroll
      for (int s = 0; s < 4; s++) {
        bf16x8 kf = *reinterpret_cast<const bf16x8*>(
            Kb + krow * 256 + ((s * 64 + l4 * 16) ^ kxm));
        sT[c] = __builtin_amdgcn_mfma_f32_16x16x32_bf16(kf, qf[s], sT[c], 0, 0, 0);
      }
    }

    // lane-local softmax (all 16 values belong to q = l15)
    const bool diag = (kv0 == q0);
    float p[4][4];
    float mx = -1e30f;
    #pragma unroll
    for (int c = 0; c < 4; c++)
      #pragma unroll
      for (int r = 0; r < 4; r++) {
        float s = sT[c][r] * 0.125f;
        if (diag) {
          int kv = kv0 + c * 16 + l4 * 4 + r;
          if (kv > qrow) s = -1e30f;
        }
        p[c][r] = s;
        mx = fmaxf(mx, s);
      }
    mx = fmaxf(mx, __shfl_xor(mx, 16));
    mx = fmaxf(mx, __shfl_xor(mx, 32));
    float m_new = fmaxf(m_run, mx);
    float corr = __expf(m_run - m_new);
    float rsum = 0.f;
    #pragma unroll
    for (int c = 0; c < 4; c++)
      #pragma unroll
      for (int r = 0; r < 4; r++) {
        float pe = __expf(p[c][r] - m_new);
        p[c][r] = pe;
        rsum += pe;
      }
    rsum += __shfl_xor(rsum, 16);
    rsum += __shfl_xor(rsum, 32);
    l_run = l_run * corr + rsum;
    m_run = m_new;
    #pragma unroll
    for (int f = 0; f < 4; f++) oT[f] *= corr;

    // P^T -> per-wave LDS roundtrip (B-frag layout)
    #pragma unroll
    for (int c = 0; c < 4; c++) {
      uint2 pk2;
      pk2.x = cvt_pk(p[c][0], p[c][1]);
      pk2.y = cvt_pk(p[c][2], p[c][3]);
      *reinterpret_cast<uint2*>(&P_lds[wave][l15][c * 16 + l4 * 4]) = pk2;
    }
    bf16x8 pb0 = *reinterpret_cast<const bf16x8*>(&P_lds[wave][l15][l4 * 8]);
    bf16x8 pb1 = *reinterpret_cast<const bf16x8*>(&P_lds[wave][l15][32 + l4 * 8]);

    // PV: O^T += V^T x P^T
    #pragma unroll
    for (int f = 0; f < 4; f++) {
      const int vrow = f * 16 + l15;
      const int vxm = (vrow & 7) << 4;
      bf16x8 v0 = *reinterpret_cast<const bf16x8*>(Vb + vrow * 128 + ((l4 * 16) ^ vxm));
      bf16x8 v1 = *reinterpret_cast<const bf16x8*>(Vb + vrow * 128 + ((64 + l4 * 16) ^ vxm));
      oT[f] = __builtin_amdgcn_mfma_f32_16x16x32_bf16(v0, pb0, oT[f], 0, 0, 0);
      oT[f] = __builtin_amdgcn_mfma_f32_16x16x32_bf16(v1, pb1, oT[f], 0, 0, 0);
    }

    __syncthreads();
    buf ^= 1;
  }

  const float inv = 1.f / l_run;
  #pragma unroll
  for (int f = 0; f < 4; f++) {
    uint2 pk2;
    pk2.x = cvt_pk(oT[f][0] * inv, oT[f][1] * inv);
    pk2.y = cvt_pk(oT[f][2] * inv, oT[f][3] * inv);
    *reinterpret_cast<uint2*>(
        &yb[(size_t)(b * T_ + qrow) * 1024 + h * 64 + f * 16 + l4 * 4]) = pk2;
  }
}

// ---------- launcher ----------
extern "C" void kernel_launch(void* const* d_in, const int* in_sizes, int n_in,
                              void* d_out, int out_size, void* d_ws, size_t ws_size,
                              hipStream_t stream) {
  const float* x         = (const float*)d_in[0];
  const float* cosT      = (const float*)d_in[1];
  const float* sinT      = (const float*)d_in[2];
  const float* W_kv_down = (const float*)d_in[3];
  const float* W_kv_up   = (const float*)d_in[4];
  const float* W_k_rope  = (const float*)d_in[5];
  const float* W_q_down  = (const float*)d_in[6];
  const float* W_q_up    = (const float*)d_in[7];
  const float* W_q_rope  = (const float*)d_in[8];
  const float* W_out     = (const float*)d_in[9];
  float* out = (float*)d_out;
  char* ws = (char*)d_ws;

  u16* xb    = (u16*)(ws + 0);              // 4096x1024 (reused as yb)
  u16* lat   = (u16*)(ws + 8388608);        // 4096x640
  u16* WdT   = (u16*)(ws + 13631488);       // 640x1024
  u16* WkvT  = (u16*)(ws + 14942208);       // 2048x256
  u16* WqT   = (u16*)(ws + 15990784);       // 2048x384
  u16* WoutT = (u16*)(ws + 17563648);       // 1024x1024
  u16* kvo   = (u16*)(ws + 19660800);       // 4096x2048 (kv_up | k_rope)
  u16* qo    = (u16*)(ws + 36438016);       // 4096x2048 (q_up | q_rope)
  u16* VT    = (u16*)(ws + 53215232);       // [2][1024][2048] V^T
  u16* yb    = (u16*)(ws + 0);

  dim3 tb(32, 8);
  conv_x_kernel<<<4096, 256, 0, stream>>>(x, xb);
  transpose_w_kernel<<<dim3(8, 32),  tb, 0, stream>>>(W_kv_down, 1024, 256,  WdT,  1024, 0);
  transpose_w_kernel<<<dim3(12, 32), tb, 0, stream>>>(W_q_down,  1024, 384,  WdT,  1024, 256);
  transpose_w_kernel<<<dim3(32, 8),  tb, 0, stream>>>(W_kv_up,   256,  1024, WkvT, 256,  0);
  transpose_w_kernel<<<dim3(32, 8),  tb, 0, stream>>>(W_k_rope,  256,  1024, WkvT, 256,  1024);
  transpose_w_kernel<<<dim3(32, 12), tb, 0, stream>>>(W_q_up,    384,  1024, WqT,  384,  0);
  transpose_w_kernel<<<dim3(32, 12), tb, 0, stream>>>(W_q_rope,  384,  1024, WqT,  384,  1024);
  transpose_w_kernel<<<dim3(32, 32), tb, 0, stream>>>(W_out,     1024, 1024, WoutT, 1024, 0);

  gemm_bt<<<dim3(5, 32), 256, 0, stream>>>(xb, 1024, WdT, 1024, lat, 640, 1024, 0, nullptr);
  gemm_bt<<<dim3(16, 32), 256, 0, stream>>>(lat, 640, WkvT, 256, kvo, 2048, 256, 0, VT);
  gemm_bt<<<dim3(16, 32), 256, 0, stream>>>(lat + 256, 640, WqT, 384, qo, 2048, 384, 0, nullptr);

  rope_kernel<<<1024, 256, 0, stream>>>(kvo, cosT, sinT);
  rope_kernel<<<1024, 256, 0, stream>>>(qo, cosT, sinT);

  attn_kernel<<<1024, 256, 0, stream>>>(qo, kvo, VT, yb);

  gemm_bt<<<dim3(8, 32), 256, 0, stream>>>(yb, 1024, WoutT, 1024, out, 1024, 1024, 1, nullptr);
}

// Round 4
// 230.980 us; speedup vs baseline: 1.7703x; 1.0777x over previous
//
#include <hip/hip_runtime.h>
#include <stdint.h>

typedef unsigned short u16;
typedef __bf16 bf16x8 __attribute__((ext_vector_type(8)));
typedef float f32x4 __attribute__((ext_vector_type(4)));

#define B_ 2
#define T_ 2048

// ---------- helpers ----------
__device__ __forceinline__ u16 f2b(float f) {
  unsigned u = __float_as_uint(f);
  u += 0x7fffu + ((u >> 16) & 1u);
  return (u16)(u >> 16);
}
__device__ __forceinline__ float b2f(u16 v) {
  return __uint_as_float(((unsigned)v) << 16);
}
__device__ __forceinline__ unsigned cvt_pk(float lo, float hi) {
  unsigned r;
  asm("v_cvt_pk_bf16_f32 %0, %1, %2" : "=v"(r) : "v"(lo), "v"(hi));
  return r;
}
__device__ __forceinline__ float ex2(float x) {  // 2^x
  float r;
  asm("v_exp_f32 %0, %1" : "=v"(r) : "v"(x));
  return r;
}

using gu32 = __attribute__((address_space(1))) const unsigned int;
using lu32 = __attribute__((address_space(3))) unsigned int;
__device__ __forceinline__ void gl_lds16(const u16* g, u16* l) {
  __builtin_amdgcn_global_load_lds((gu32*)g, (lu32*)l, 16, 0, 0);
}

// ---------- convert x fp32 -> bf16 ----------
__global__ __launch_bounds__(256) void conv_x_kernel(const float* __restrict__ in,
                                                     u16* __restrict__ out) {
  int i = (blockIdx.x * 256 + threadIdx.x) * 4;
  float4 v = *reinterpret_cast<const float4*>(in + i);
  union { u16 h[4]; unsigned long long ll; } pk;
  pk.h[0] = f2b(v.x); pk.h[1] = f2b(v.y); pk.h[2] = f2b(v.z); pk.h[3] = f2b(v.w);
  *reinterpret_cast<unsigned long long*>(out + i) = pk.ll;
}

// ---------- fused all-weight transpose: fp32 [K][N] -> bf16 Wt[row_off+n][k] ----------
struct TJob { const float* src; u16* dst; int K, N, ldt, row_off, blk0; };
struct TJobs { TJob j[7]; };

__global__ __launch_bounds__(256) void transpose_all_kernel(TJobs jobs) {
  __shared__ float tile[32][33];
  int bid = blockIdx.x;
  int ji = 0;
  #pragma unroll
  for (int i = 6; i > 0; --i)
    if (bid >= jobs.j[i].blk0) { ji = i; break; }
  const TJob jb = jobs.j[ji];
  int local = bid - jb.blk0;
  int nb = jb.N >> 5;
  int n0 = (local % nb) * 32, k0 = (local / nb) * 32;
  int cx = threadIdx.x, ry = threadIdx.y;
  #pragma unroll
  for (int i = 0; i < 4; i++)
    tile[ry + i * 8][cx] = jb.src[(size_t)(k0 + ry + i * 8) * jb.N + n0 + cx];
  __syncthreads();
  #pragma unroll
  for (int i = 0; i < 4; i++)
    jb.dst[(size_t)(jb.row_off + n0 + ry + i * 8) * jb.ldt + k0 + cx] =
        f2b(tile[cx][ry + i * 8]);
}

// ---------- GEMM (2-phase dbuf) with fused epilogues ----------
// mode: 0 = bf16 out; 1 = f32 out; 2 = kvo (VT copy col<1024, rope col>=1024);
//       3 = qo (rope col>=1024)
__global__ __launch_bounds__(256) void gemm_bt(const u16* __restrict__ A, int lda,
                                               const u16* __restrict__ Bt, int ldb,
                                               void* __restrict__ Cout, int ldc,
                                               int K, int mode, u16* __restrict__ vt,
                                               const float* __restrict__ cosT,
                                               const float* __restrict__ sinT) {
  __shared__ u16 As[2][128 * 32];
  __shared__ u16 Bs[2][128 * 32];
  const int tid = threadIdx.x;
  const int wave = tid >> 6, lane = tid & 63;
  const int wr = wave >> 1, wc = wave & 1;
  const int l15 = lane & 15, l4 = lane >> 4;
  const int m0 = blockIdx.y * 128, n0 = blockIdx.x * 128;
  const int lr = lane >> 2;
  const int lc = (lane & 3) * 8;

  f32x4 acc[4][4];
  const f32x4 fzero = {0.f, 0.f, 0.f, 0.f};
  #pragma unroll
  for (int m = 0; m < 4; m++)
    #pragma unroll
    for (int n = 0; n < 4; n++)
      acc[m][n] = fzero;

  const u16* gA  = A  + (size_t)(m0 + wave * 32 + lr) * lda + lc;
  const u16* gA2 = gA + (size_t)16 * lda;
  const u16* gB  = Bt + (size_t)(n0 + wave * 32 + lr) * ldb + lc;
  const u16* gB2 = gB + (size_t)16 * ldb;

  auto stage = [&](int buf, int k0) {
    gl_lds16(gA + k0, &As[buf][(wave * 32) * 32]);
    gl_lds16(gA2 + k0, &As[buf][(wave * 32 + 16) * 32]);
    gl_lds16(gB + k0, &Bs[buf][(wave * 32) * 32]);
    gl_lds16(gB2 + k0, &Bs[buf][(wave * 32 + 16) * 32]);
  };

  stage(0, 0);
  __syncthreads();
  int buf = 0;
  for (int k0 = 0; k0 < K; k0 += 32) {
    if (k0 + 32 < K) stage(buf ^ 1, k0 + 32);
    bf16x8 af[4], bfr[4];
    #pragma unroll
    for (int m = 0; m < 4; m++)
      af[m] = *reinterpret_cast<const bf16x8*>(&As[buf][(wr * 64 + m * 16 + l15) * 32 + l4 * 8]);
    #pragma unroll
    for (int n = 0; n < 4; n++)
      bfr[n] = *reinterpret_cast<const bf16x8*>(&Bs[buf][(wc * 64 + n * 16 + l15) * 32 + l4 * 8]);
    #pragma unroll
    for (int m = 0; m < 4; m++)
      #pragma unroll
      for (int n = 0; n < 4; n++)
        acc[m][n] = __builtin_amdgcn_mfma_f32_16x16x32_bf16(af[m], bfr[n], acc[m][n], 0, 0, 0);
    __syncthreads();
    buf ^= 1;
  }

  const int row_base = m0 + wr * 64 + l4 * 4;
  const int col_base = n0 + wc * 64 + l15;

  if (mode == 1) {
    float* Cf = (float*)Cout;
    #pragma unroll
    for (int m = 0; m < 4; m++)
      #pragma unroll
      for (int n = 0; n < 4; n++)
        #pragma unroll
        for (int r = 0; r < 4; r++)
          Cf[(size_t)(row_base + m * 16 + r) * ldc + col_base + n * 16] = acc[m][n][r];
    return;
  }

  // fused rope on the rope half (cols >= 1024), in f32 before quantization.
  // lane's 4 col-quadrants are i = l15, l15+16, l15+32, l15+48 -> pairs (0,2),(1,3)
  if (mode >= 2 && (n0 + wc * 64) >= 1024) {
    #pragma unroll
    for (int m = 0; m < 4; m++)
      #pragma unroll
      for (int r = 0; r < 4; r++) {
        int t = (row_base + m * 16 + r) & (T_ - 1);
        const float* cp = cosT + t * 64 + l15;
        const float* sp = sinT + t * 64 + l15;
        float c0 = cp[0], c16 = cp[16], c32 = cp[32], c48 = cp[48];
        float s0 = sp[0], s16 = sp[16], s32 = sp[32], s48 = sp[48];
        float x0 = acc[m][0][r], x1 = acc[m][1][r];
        float x2 = acc[m][2][r], x3 = acc[m][3][r];
        acc[m][0][r] = x0 * c0 - x2 * s0;
        acc[m][1][r] = x1 * c16 - x3 * s16;
        acc[m][2][r] = x2 * c32 + x0 * s32;
        acc[m][3][r] = x3 * c48 + x1 * s48;
      }
  }

  u16* Cb = (u16*)Cout;
  #pragma unroll
  for (int m = 0; m < 4; m++)
    #pragma unroll
    for (int n = 0; n < 4; n++)
      #pragma unroll
      for (int r = 0; r < 4; r++)
        Cb[(size_t)(row_base + m * 16 + r) * ldc + col_base + n * 16] = f2b(acc[m][n][r]);

  if (mode == 2) {
    // transposed copy of V content cols: VT[(b*1024+col)][t]
    #pragma unroll
    for (int m = 0; m < 4; m++)
      #pragma unroll
      for (int n = 0; n < 4; n++) {
        int col = col_base + n * 16;
        if (col < 1024) {
          int mm = row_base + m * 16;
          int bb = mm >> 11, tt = mm & 2047;
          uint2 pk2;
          pk2.x = cvt_pk(acc[m][n][0], acc[m][n][1]);
          pk2.y = cvt_pk(acc[m][n][2], acc[m][n][3]);
          *reinterpret_cast<uint2*>(&vt[(size_t)(bb * 1024 + col) * 2048 + tt]) = pk2;
        }
      }
  }
}

// ---------- causal flash attention: QBLK=128, 8 waves ----------
// swapped QK^T (lane-local softmax), swizzled K/V LDS via pre-swizzled
// global_load_lds source, 2-phase dbuf, defer-max, base-2 softmax.
// grid 512 x 512 thr; bh = bid&31 (XCD locality), qi = 15-(bid>>5) (LPT).
__global__ __launch_bounds__(512) void attn_kernel(const u16* __restrict__ qo,
                                                   const u16* __restrict__ kvo,
                                                   const u16* __restrict__ vtg,
                                                   u16* __restrict__ yb) {
  __shared__ u16 K_lds[2][64 * 128];   // rows swizzled: byte ^= (row&7)<<4
  __shared__ u16 V_lds[2][64 * 64];    // V^T, same swizzle
  __shared__ u16 P_lds[8][16][72];
  const int tid = threadIdx.x;
  const int wave = tid >> 6, lane = tid & 63;
  const int l15 = lane & 15, l4 = lane >> 4;
  const int bid = blockIdx.x;
  const int bh = bid & 31;
  const int qi = 15 - (bid >> 5);
  const int b = bh >> 4, h = bh & 15;
  const int q0 = qi * 128;
  const int qrow = q0 + wave * 16 + l15;

  const u16* qb = qo + (size_t)(b * T_ + qrow) * 2048 + h * 64;
  bf16x8 qf[4];
  qf[0] = *reinterpret_cast<const bf16x8*>(qb + l4 * 8);
  qf[1] = *reinterpret_cast<const bf16x8*>(qb + 32 + l4 * 8);
  qf[2] = *reinterpret_cast<const bf16x8*>(qb + 1024 + l4 * 8);
  qf[3] = *reinterpret_cast<const bf16x8*>(qb + 1056 + l4 * 8);

  const u16* Kbase = kvo + (size_t)(b * T_) * 2048 + h * 64;
  const u16* Vbase = vtg + (size_t)(b * 1024 + h * 64) * 2048;

  const int krow_i = lane >> 4;         // K: 4 rows/issue, 2 issues -> 8 rows/wave
  const int kc2 = (lane & 15) * 16;
  const int vrow_i = lane >> 3;         // V: 8 rows in 1 issue
  const int vc2 = (lane & 7) * 16;

  auto stage = [&](int buf, int kv0) {
    #pragma unroll
    for (int j = 0; j < 2; j++) {
      int row = wave * 8 + j * 4 + krow_i;
      int c2x = kc2 ^ ((row & 7) << 4);
      int cu = c2x >> 1;
      const u16* src = Kbase + (size_t)(kv0 + row) * 2048 + (cu < 64 ? cu : 960 + cu);
      gl_lds16(src, &K_lds[buf][(wave * 8 + j * 4) * 128]);
    }
    {
      int row = wave * 8 + vrow_i;
      int c2x = vc2 ^ ((row & 7) << 4);
      const u16* src = Vbase + (size_t)row * 2048 + kv0 + (c2x >> 1);
      gl_lds16(src, &V_lds[buf][(wave * 8) * 64]);
    }
  };

  const f32x4 fzero = {0.f, 0.f, 0.f, 0.f};
  f32x4 oT[4];
  #pragma unroll
  for (int f = 0; f < 4; f++) oT[f] = fzero;
  float m_run = -1e30f, l_run = 0.f;

  const float SCALE2 = 0.125f * 1.44269504f;   // 1/sqrt(64) * log2(e)
  const int nt = qi * 2 + 2;
  const int t_diag = qi * 2 + (wave >> 2);     // wave's diagonal tile index

  stage(0, 0);
  __syncthreads();
  int buf = 0;

  for (int t = 0; t < nt; t++) {
    const int kv0 = t * 64;
    if (t + 1 < nt) stage(buf ^ 1, kv0 + 64);

    if (t <= t_diag) {
      const char* Kb = (const char*)&K_lds[buf][0];
      const char* Vb = (const char*)&V_lds[buf][0];

      f32x4 sT[4];
      #pragma unroll
      for (int c = 0; c < 4; c++) sT[c] = fzero;
      #pragma unroll
      for (int c = 0; c < 4; c++) {
        const int krow = c * 16 + l15;
        const int kxm = (krow & 7) << 4;
        #pragma unroll
        for (int s = 0; s < 4; s++) {
          bf16x8 kf = *reinterpret_cast<const bf16x8*>(
              Kb + krow * 256 + ((s * 64 + l4 * 16) ^ kxm));
          sT[c] = __builtin_amdgcn_mfma_f32_16x16x32_bf16(kf, qf[s], sT[c], 0, 0, 0);
        }
      }

      const bool diag = (t == t_diag);
      float p[4][4];
      float mx = -1e30f;
      #pragma unroll
      for (int c = 0; c < 4; c++)
        #pragma unroll
        for (int r = 0; r < 4; r++) {
          float s = sT[c][r] * SCALE2;
          if (diag) {
            int kv = kv0 + c * 16 + l4 * 4 + r;
            if (kv > qrow) s = -1e30f;
          }
          p[c][r] = s;
          mx = fmaxf(mx, s);
        }
      mx = fmaxf(mx, __shfl_xor(mx, 16));
      mx = fmaxf(mx, __shfl_xor(mx, 32));
      if (__any(mx > m_run + 11.5f)) {         // defer-max (T13)
        float m_new = fmaxf(m_run, mx);
        float corr = ex2(m_run - m_new);
        l_run *= corr;
        #pragma unroll
        for (int f = 0; f < 4; f++) oT[f] *= corr;
        m_run = m_new;
      }
      float rsum = 0.f;
      #pragma unroll
      for (int c = 0; c < 4; c++)
        #pragma unroll
        for (int r = 0; r < 4; r++) {
          float pe = ex2(p[c][r] - m_run);
          p[c][r] = pe;
          rsum += pe;
        }
      rsum += __shfl_xor(rsum, 16);
      rsum += __shfl_xor(rsum, 32);
      l_run += rsum;

      #pragma unroll
      for (int c = 0; c < 4; c++) {
        uint2 pk2;
        pk2.x = cvt_pk(p[c][0], p[c][1]);
        pk2.y = cvt_pk(p[c][2], p[c][3]);
        *reinterpret_cast<uint2*>(&P_lds[wave][l15][c * 16 + l4 * 4]) = pk2;
      }
      bf16x8 pb0 = *reinterpret_cast<const bf16x8*>(&P_lds[wave][l15][l4 * 8]);
      bf16x8 pb1 = *reinterpret_cast<const bf16x8*>(&P_lds[wave][l15][32 + l4 * 8]);

      #pragma unroll
      for (int f = 0; f < 4; f++) {
        const int vrow = f * 16 + l15;
        const int vxm = (vrow & 7) << 4;
        bf16x8 v0 = *reinterpret_cast<const bf16x8*>(Vb + vrow * 128 + ((l4 * 16) ^ vxm));
        bf16x8 v1 = *reinterpret_cast<const bf16x8*>(Vb + vrow * 128 + ((64 + l4 * 16) ^ vxm));
        oT[f] = __builtin_amdgcn_mfma_f32_16x16x32_bf16(v0, pb0, oT[f], 0, 0, 0);
        oT[f] = __builtin_amdgcn_mfma_f32_16x16x32_bf16(v1, pb1, oT[f], 0, 0, 0);
      }
    }

    __syncthreads();
    buf ^= 1;
  }

  const float inv = 1.f / l_run;
  #pragma unroll
  for (int f = 0; f < 4; f++) {
    uint2 pk2;
    pk2.x = cvt_pk(oT[f][0] * inv, oT[f][1] * inv);
    pk2.y = cvt_pk(oT[f][2] * inv, oT[f][3] * inv);
    *reinterpret_cast<uint2*>(
        &yb[(size_t)(b * T_ + qrow) * 1024 + h * 64 + f * 16 + l4 * 4]) = pk2;
  }
}

// ---------- launcher ----------
extern "C" void kernel_launch(void* const* d_in, const int* in_sizes, int n_in,
                              void* d_out, int out_size, void* d_ws, size_t ws_size,
                              hipStream_t stream) {
  const float* x         = (const float*)d_in[0];
  const float* cosT      = (const float*)d_in[1];
  const float* sinT      = (const float*)d_in[2];
  const float* W_kv_down = (const float*)d_in[3];
  const float* W_kv_up   = (const float*)d_in[4];
  const float* W_k_rope  = (const float*)d_in[5];
  const float* W_q_down  = (const float*)d_in[6];
  const float* W_q_up    = (const float*)d_in[7];
  const float* W_q_rope  = (const float*)d_in[8];
  const float* W_out     = (const float*)d_in[9];
  float* out = (float*)d_out;
  char* ws = (char*)d_ws;

  u16* xb    = (u16*)(ws + 0);              // 4096x1024 (reused as yb)
  u16* lat   = (u16*)(ws + 8388608);        // 4096x640
  u16* WdT   = (u16*)(ws + 13631488);       // 640x1024
  u16* WkvT  = (u16*)(ws + 14942208);       // 2048x256
  u16* WqT   = (u16*)(ws + 15990784);       // 2048x384
  u16* WoutT = (u16*)(ws + 17563648);       // 1024x1024
  u16* kvo   = (u16*)(ws + 19660800);       // 4096x2048 (kv_up | k_rope)
  u16* qo    = (u16*)(ws + 36438016);       // 4096x2048 (q_up | q_rope)
  u16* VT    = (u16*)(ws + 53215232);       // [2][1024][2048] V^T
  u16* yb    = (u16*)(ws + 0);

  conv_x_kernel<<<4096, 256, 0, stream>>>(x, xb);

  TJobs jobs;
  jobs.j[0] = {W_kv_down, WdT,   1024, 256,  1024, 0,    0};
  jobs.j[1] = {W_q_down,  WdT,   1024, 384,  1024, 256,  256};
  jobs.j[2] = {W_kv_up,   WkvT,  256,  1024, 256,  0,    640};
  jobs.j[3] = {W_k_rope,  WkvT,  256,  1024, 256,  1024, 896};
  jobs.j[4] = {W_q_up,    WqT,   384,  1024, 384,  0,    1152};
  jobs.j[5] = {W_q_rope,  WqT,   384,  1024, 384,  1024, 1536};
  jobs.j[6] = {W_out,     WoutT, 1024, 1024, 1024, 0,    1920};
  transpose_all_kernel<<<2944, dim3(32, 8), 0, stream>>>(jobs);

  // lat = xb @ [W_kv_down | W_q_down]
  gemm_bt<<<dim3(5, 32), 256, 0, stream>>>(xb, 1024, WdT, 1024, lat, 640, 1024, 0,
                                           nullptr, nullptr, nullptr);
  // kvo = lat[:,:256] @ [W_kv_up | W_k_rope]  (+VT copy, +rope on cols>=1024)
  gemm_bt<<<dim3(16, 32), 256, 0, stream>>>(lat, 640, WkvT, 256, kvo, 2048, 256, 2,
                                            VT, cosT, sinT);
  // qo = lat[:,256:] @ [W_q_up | W_q_rope]  (+rope on cols>=1024)
  gemm_bt<<<dim3(16, 32), 256, 0, stream>>>(lat + 256, 640, WqT, 384, qo, 2048, 384, 3,
                                            nullptr, cosT, sinT);

  attn_kernel<<<512, 512, 0, stream>>>(qo, kvo, VT, yb);

  // out = yb @ W_out (fp32)
  gemm_bt<<<dim3(8, 32), 256, 0, stream>>>(yb, 1024, WoutT, 1024, out, 1024, 1024, 1,
                                           nullptr, nullptr, nullptr);
}